// Round 7
// baseline (1684.216 us; speedup 1.0000x reference)
//
#include <hip/hip_runtime.h>
#include <hip/hip_bf16.h>
#include <math.h>

// ---------------------------------------------------------------------------
// MLA prefill. Round 7: 128x128 split-bf16 GEMM; attention LDS XOR-swizzle
// (conflict-free staging), 50KB LDS -> 3 blocks/CU. Workspace 161.5 MB.
// ---------------------------------------------------------------------------

#define T_TOK   4096
#define SEQ_LEN 2048
#define NB      2
#define NHEAD   16
#define DMODEL  2048
#define DCQ     1536
#define DCKV    512
#define DROPE   64
#define QHD     192
#define MEGD    256

typedef unsigned short u16;
typedef unsigned int   u32;
typedef __attribute__((ext_vector_type(8))) short short8v;
typedef __attribute__((ext_vector_type(4))) float f32x4;

__device__ __forceinline__ u16 f2bf(float f) {
    u32 u = __float_as_uint(f);
    u32 r = u + 0x7FFFu + ((u >> 16) & 1u);   // RNE
    return (u16)(r >> 16);
}
__device__ __forceinline__ float bf2f(u16 h) {
    return __uint_as_float(((u32)h) << 16);
}

// ----------------------- split-bf16 MFMA GEMM (128x128) ---------------------
// C[m][n] = sum_k A[m][k]*W[n][k]; on-the-fly (hi,lo) split during staging;
// C ~= Ah*Wh + Ah*Wl + Al*Wh. BM=BN=128, BK=32, 4 waves 2x2, each 64x64 out
// (4x4 fragments of 16x16x32). LDS stride 40 u16 (80B) -> uniform bank use.
// Verified MFMA layouts (R5/R6 passed):
//   A/B frag: lane l elem j = M[l&15][(l>>4)*8 + j]
//   C/D:      col = l&15, row = 4*(l>>4) + reg
#define GSTR 40

__global__ __launch_bounds__(256) void gemm_split_nt(
    const float* __restrict__ A, int lda,
    const float* __restrict__ W, int ldw,
    float* __restrict__ C, int ldc, int K, int N)
{
    __shared__ __align__(16) u16 Ahs[128][GSTR];
    __shared__ __align__(16) u16 Als[128][GSTR];
    __shared__ __align__(16) u16 Whs[128][GSTR];
    __shared__ __align__(16) u16 Wls[128][GSTR];

    const int tid  = threadIdx.x;
    const int wave = tid >> 6;
    const int lane = tid & 63;
    const int wr = (wave >> 1) * 64;
    const int wc = (wave & 1) * 64;
    const int m0 = blockIdx.y * 128;
    const int n0 = blockIdx.x * 128;
    const int fr = lane & 15;
    const int kg = (lane >> 4) * 8;

    f32x4 acc[4][4];
    #pragma unroll
    for (int i = 0; i < 4; ++i)
        #pragma unroll
        for (int j = 0; j < 4; ++j)
            acc[i][j] = (f32x4){0.f, 0.f, 0.f, 0.f};

    // staging: slots s = tid, tid+256; row = s>>2, col8 = (s&3)*8
    const int r0 = tid >> 2,          c0 = (tid & 3) * 8;
    const int r1 = (tid + 256) >> 2,  c1 = c0;            // r1 = r0 + 64
    const int an0 = m0 + r0, an1 = m0 + r1;
    const int wn0 = (n0 + r0 < N) ? n0 + r0 : N - 1;      // clamp (kv_down tile)
    const int wn1 = (n0 + r1 < N) ? n0 + r1 : N - 1;

    for (int k0 = 0; k0 < K; k0 += 32) {
        float a0[8], a1[8], w0[8], w1[8];
        *(float4*)&a0[0] = *(const float4*)(A + (size_t)an0 * lda + k0 + c0);
        *(float4*)&a0[4] = *(const float4*)(A + (size_t)an0 * lda + k0 + c0 + 4);
        *(float4*)&a1[0] = *(const float4*)(A + (size_t)an1 * lda + k0 + c1);
        *(float4*)&a1[4] = *(const float4*)(A + (size_t)an1 * lda + k0 + c1 + 4);
        *(float4*)&w0[0] = *(const float4*)(W + (size_t)wn0 * ldw + k0 + c0);
        *(float4*)&w0[4] = *(const float4*)(W + (size_t)wn0 * ldw + k0 + c0 + 4);
        *(float4*)&w1[0] = *(const float4*)(W + (size_t)wn1 * ldw + k0 + c1);
        *(float4*)&w1[4] = *(const float4*)(W + (size_t)wn1 * ldw + k0 + c1 + 4);

        short8v a0h, a0l, a1h, a1l, w0h, w0l, w1h, w1l;
        #pragma unroll
        for (int j = 0; j < 8; ++j) {
            u16 hb;
            hb = f2bf(a0[j]); a0h[j] = (short)hb; a0l[j] = (short)f2bf(a0[j] - bf2f(hb));
            hb = f2bf(a1[j]); a1h[j] = (short)hb; a1l[j] = (short)f2bf(a1[j] - bf2f(hb));
            hb = f2bf(w0[j]); w0h[j] = (short)hb; w0l[j] = (short)f2bf(w0[j] - bf2f(hb));
            hb = f2bf(w1[j]); w1h[j] = (short)hb; w1l[j] = (short)f2bf(w1[j] - bf2f(hb));
        }
        __syncthreads();
        *(short8v*)&Ahs[r0][c0] = a0h;  *(short8v*)&Als[r0][c0] = a0l;
        *(short8v*)&Ahs[r1][c1] = a1h;  *(short8v*)&Als[r1][c1] = a1l;
        *(short8v*)&Whs[r0][c0] = w0h;  *(short8v*)&Wls[r0][c0] = w0l;
        *(short8v*)&Whs[r1][c1] = w1h;  *(short8v*)&Wls[r1][c1] = w1l;
        __syncthreads();

        short8v wfh[4], wfl[4];
        #pragma unroll
        for (int nj = 0; nj < 4; ++nj) {
            wfh[nj] = *(const short8v*)&Whs[wc + nj * 16 + fr][kg];
            wfl[nj] = *(const short8v*)&Wls[wc + nj * 16 + fr][kg];
        }
        #pragma unroll
        for (int mi = 0; mi < 4; ++mi) {
            short8v ah = *(const short8v*)&Ahs[wr + mi * 16 + fr][kg];
            short8v al = *(const short8v*)&Als[wr + mi * 16 + fr][kg];
            #pragma unroll
            for (int nj = 0; nj < 4; ++nj) {
                acc[mi][nj] = __builtin_amdgcn_mfma_f32_16x16x32_bf16(ah, wfh[nj], acc[mi][nj], 0, 0, 0);
                acc[mi][nj] = __builtin_amdgcn_mfma_f32_16x16x32_bf16(ah, wfl[nj], acc[mi][nj], 0, 0, 0);
                acc[mi][nj] = __builtin_amdgcn_mfma_f32_16x16x32_bf16(al, wfh[nj], acc[mi][nj], 0, 0, 0);
            }
        }
    }

    const int rq = (lane >> 4) * 4;
    #pragma unroll
    for (int mi = 0; mi < 4; ++mi)
        #pragma unroll
        for (int nj = 0; nj < 4; ++nj) {
            const int col = n0 + wc + nj * 16 + fr;
            if (col < N) {
                #pragma unroll
                for (int r = 0; r < 4; ++r)
                    C[(size_t)(m0 + wr + mi * 16 + rq + r) * ldc + col] = acc[mi][nj][r];
            }
        }
}

// ------------------------------ RMSNorm ------------------------------------
template <int NPT>
__global__ __launch_bounds__(256) void rmsnorm_kernel(
    float* __restrict__ data, int stride, const float* __restrict__ w, int width)
{
    const int row = blockIdx.x;
    float* p = data + (size_t)row * stride;
    const int tid = threadIdx.x;

    float v[NPT];
    float ss = 0.f;
    #pragma unroll
    for (int i = 0; i < NPT; ++i) { v[i] = p[tid + i * 256]; ss += v[i] * v[i]; }
    #pragma unroll
    for (int off = 32; off; off >>= 1) ss += __shfl_xor(ss, off, 64);

    __shared__ float red[4];
    if ((tid & 63) == 0) red[tid >> 6] = ss;
    __syncthreads();
    ss = red[0] + red[1] + red[2] + red[3];

    const float scale = rsqrtf(ss / (float)width + 1e-7f);
    #pragma unroll
    for (int i = 0; i < NPT; ++i)
        p[tid + i * 256] = w[tid + i * 256] * (v[i] * scale);
}

// -------------------------------- RoPE -------------------------------------
// freq table computed once per block in LDS (32 powf total, not per thread).
__device__ __forceinline__ void rope_row(const float* __restrict__ vin,
                                         float* __restrict__ vout, float p,
                                         const float* __restrict__ ftab)
{
    float buf[64];
    #pragma unroll
    for (int j = 0; j < 64; ++j) buf[j] = vin[j];
    #pragma unroll
    for (int j = 0; j < 32; ++j) {
        float a = p * ftab[j];
        float c = cosf(a), s = sinf(a);
        vout[j]      = buf[2 * j] * c - buf[2 * j + 1] * s;
        vout[32 + j] = buf[2 * j + 1] * c + buf[2 * j] * s;
    }
}

__global__ __launch_bounds__(256) void rope_q_kernel(float* __restrict__ q,
                                                     const int* __restrict__ pos)
{
    __shared__ float ftab[32];
    if (threadIdx.x < 32)
        ftab[threadIdx.x] = powf(10000.f, -(float)threadIdx.x * (1.f / 32.f));
    __syncthreads();
    const int idx = blockIdx.x * 256 + threadIdx.x;
    if (idx >= T_TOK * NHEAD) return;
    const int t = idx >> 4, h = idx & 15;
    float* v = q + (size_t)t * (NHEAD * QHD) + h * QHD + 128;
    rope_row(v, v, (float)pos[t], ftab);
}

__global__ __launch_bounds__(256) void rope_k_kernel(const float* __restrict__ ckv,
                                                     const int* __restrict__ pos,
                                                     float* __restrict__ kr)
{
    __shared__ float ftab[32];
    if (threadIdx.x < 32)
        ftab[threadIdx.x] = powf(10000.f, -(float)threadIdx.x * (1.f / 32.f));
    __syncthreads();
    const int t = blockIdx.x * 256 + threadIdx.x;
    if (t >= T_TOK) return;
    rope_row(ckv + (size_t)t * (DCKV + DROPE) + DCKV, kr + (size_t)t * DROPE,
             (float)pos[t], ftab);
}

// ---------------------- MFMA flash attention (split-bf16) -------------------
// BQ=64, BKT=32, 256 thr = 4 waves; wave w owns q-rows [w*16, w*16+16).
// K: [32][192] u16, 384B rows (3x128B) + XOR swizzle (row&7)<<4 on byte addr
//    -> bijective (row stride % 128 == 0), conflict-free 16B writes, 2-way reads.
// V^T: [128][32] u16, 64B rows + same XOR -> bijective, conflict-free reads.
// P: per-wave [16][40]. Split 3-product everywhere (fp32-grade).
#define BQA   64
#define BKA   32
#define PSTR2 40

#define KSWZ(row, colu16) ((((row) * 192 + (colu16)) * 2) ^ (((row) & 7) << 4))
#define VSWZ(row, colu16) ((((row) * 32 + (colu16)) * 2) ^ (((row) & 7) << 4))

__global__ __launch_bounds__(256) void mla_attn_mfma(
    const float* __restrict__ q,    // [T, 3072] (rope applied)
    const float* __restrict__ kv,   // [T, 4096]
    const float* __restrict__ kr,   // [T, 64]
    float* __restrict__ o)          // [T, 2048]
{
    __shared__ __align__(128) u16 KhS[32 * 192];
    __shared__ __align__(128) u16 KlS[32 * 192];
    __shared__ __align__(128) u16 VhS[128 * 32];
    __shared__ __align__(128) u16 VlS[128 * 32];
    __shared__ __align__(16) u16 PhS[4][16][PSTR2];
    __shared__ __align__(16) u16 PlS[4][16][PSTR2];

    const int qt = (int)(gridDim.x - 1) - (int)blockIdx.x;  // heavy blocks first
    const int h  = blockIdx.y;
    const int b  = blockIdx.z;
    const int q0 = qt * BQA;
    const int tid  = threadIdx.x;
    const int wave = tid >> 6;
    const int lane = tid & 63;
    const int fr = lane & 15;
    const int gp = lane >> 4;        // 0..3
    const int kg = gp * 8;           // fragment k-offset (u16)

    char* KhB = (char*)&KhS[0];
    char* KlB = (char*)&KlS[0];
    char* VhB = (char*)&VhS[0];
    char* VlB = (char*)&VlS[0];

    // ---- Q fragments (rows q0 + wave*16 + fr), split hi/lo in registers
    short8v qh[6], ql[6];
    {
        const float* qrow = q + (size_t)(b * SEQ_LEN + q0 + wave * 16 + fr) * (NHEAD * QHD)
                              + h * QHD;
        #pragma unroll
        for (int ks = 0; ks < 6; ++ks) {
            float v8[8];
            *(float4*)&v8[0] = *(const float4*)(qrow + ks * 32 + kg);
            *(float4*)&v8[4] = *(const float4*)(qrow + ks * 32 + kg + 4);
            #pragma unroll
            for (int j = 0; j < 8; ++j) {
                u16 hb = f2bf(v8[j]);
                qh[ks][j] = (short)hb;
                ql[ks][j] = (short)f2bf(v8[j] - bf2f(hb));
            }
        }
    }

    f32x4 acc_o[8];
    #pragma unroll
    for (int i = 0; i < 8; ++i) acc_o[i] = (f32x4){0.f, 0.f, 0.f, 0.f};
    float mrow[4] = {-1e30f, -1e30f, -1e30f, -1e30f};
    float lrow[4] = {0.f, 0.f, 0.f, 0.f};

    const float scale = 0.07216878364870323f;  // 1/sqrt(192)
    const int ntile = 2 * qt + 2;
    const int qmax_w = q0 + 16 * wave + 15;

    for (int kt = 0; kt < ntile; ++kt) {
        const int k0 = kt * BKA;
        __syncthreads();   // prev tile's LDS reads complete

        // ---- stage K [32 rows][192 cols] hi/lo, 16B units, swizzled
        #pragma unroll
        for (int i = 0; i < 3; ++i) {
            const int s = tid + 256 * i;        // 0..767
            const int krow = s / 24;
            const int c = (s % 24) * 8;         // u16 col: 0..184
            const int tk = b * SEQ_LEN + k0 + krow;
            float v8[8];
            if (c < 128) {
                const float* src = kv + (size_t)tk * (NHEAD * MEGD) + h * MEGD + c;
                *(float4*)&v8[0] = *(const float4*)(src);
                *(float4*)&v8[4] = *(const float4*)(src + 4);
            } else {
                const float* src = kr + (size_t)tk * DROPE + (c - 128);
                *(float4*)&v8[0] = *(const float4*)(src);
                *(float4*)&v8[4] = *(const float4*)(src + 4);
            }
            short8v hh, ll;
            #pragma unroll
            for (int j = 0; j < 8; ++j) {
                u16 hb = f2bf(v8[j]);
                hh[j] = (short)hb;
                ll[j] = (short)f2bf(v8[j] - bf2f(hb));
            }
            const int bo = KSWZ(krow, c);
            *(short8v*)(KhB + bo) = hh;
            *(short8v*)(KlB + bo) = ll;
        }
        // ---- stage V transposed [128 d][32 k] hi/lo via 4x4 micro-transpose
        {
            const int kq = (tid & 7) * 4;     // k quad base
            const int dq = (tid >> 3) * 4;    // d quad base
            float4 vv[4];
            #pragma unroll
            for (int r = 0; r < 4; ++r) {
                const int tk = b * SEQ_LEN + k0 + kq + r;
                vv[r] = *(const float4*)(kv + (size_t)tk * (NHEAD * MEGD) + h * MEGD + 128 + dq);
            }
            const float* vp = (const float*)&vv[0];
            #pragma unroll
            for (int i = 0; i < 4; ++i) {     // d offset
                ushort4 hh, ll;
                u16* hp = &hh.x; u16* lp = &ll.x;
                #pragma unroll
                for (int r = 0; r < 4; ++r) { // k offset
                    float f = vp[r * 4 + i];
                    u16 hb = f2bf(f);
                    hp[r] = hb;
                    lp[r] = f2bf(f - bf2f(hb));
                }
                const int bo = VSWZ(dq + i, kq);
                *(ushort4*)(VhB + bo) = hh;
                *(ushort4*)(VlB + bo) = ll;
            }
        }
        __syncthreads();   // tiles staged

        if (k0 <= qmax_w) {
            // ---- scores: S[16][32] = Q(16x192) . K^T, split 3-product
            f32x4 s0 = (f32x4){0.f, 0.f, 0.f, 0.f};
            f32x4 s1 = (f32x4){0.f, 0.f, 0.f, 0.f};
            #pragma unroll
            for (int ks = 0; ks < 6; ++ks) {
                const int b0 = KSWZ(fr,      ks * 32 + kg);
                const int b1 = KSWZ(fr + 16, ks * 32 + kg);
                short8v kh0 = *(const short8v*)(KhB + b0);
                short8v kl0 = *(const short8v*)(KlB + b0);
                short8v kh1 = *(const short8v*)(KhB + b1);
                short8v kl1 = *(const short8v*)(KlB + b1);
                s0 = __builtin_amdgcn_mfma_f32_16x16x32_bf16(qh[ks], kh0, s0, 0, 0, 0);
                s0 = __builtin_amdgcn_mfma_f32_16x16x32_bf16(qh[ks], kl0, s0, 0, 0, 0);
                s0 = __builtin_amdgcn_mfma_f32_16x16x32_bf16(ql[ks], kh0, s0, 0, 0, 0);
                s1 = __builtin_amdgcn_mfma_f32_16x16x32_bf16(qh[ks], kh1, s1, 0, 0, 0);
                s1 = __builtin_amdgcn_mfma_f32_16x16x32_bf16(qh[ks], kl1, s1, 0, 0, 0);
                s1 = __builtin_amdgcn_mfma_f32_16x16x32_bf16(ql[ks], kh1, s1, 0, 0, 0);
            }
            // ---- mask + online softmax (rows 4*gp+r, cols fr / fr+16)
            float alpha[4];
            #pragma unroll
            for (int r = 0; r < 4; ++r) {
                const int qglob = q0 + wave * 16 + 4 * gp + r;
                float sc0 = (k0 + fr      <= qglob) ? s0[r] * scale : -1e30f;
                float sc1 = (k0 + 16 + fr <= qglob) ? s1[r] * scale : -1e30f;
                float mt = fmaxf(sc0, sc1);
                mt = fmaxf(mt, __shfl_xor(mt, 1, 64));
                mt = fmaxf(mt, __shfl_xor(mt, 2, 64));
                mt = fmaxf(mt, __shfl_xor(mt, 4, 64));
                mt = fmaxf(mt, __shfl_xor(mt, 8, 64));
                const float mnew = fmaxf(mrow[r], mt);
                alpha[r] = __expf(mrow[r] - mnew);
                const float p0 = __expf(sc0 - mnew);
                const float p1 = __expf(sc1 - mnew);
                float ps = p0 + p1;
                ps += __shfl_xor(ps, 1, 64);
                ps += __shfl_xor(ps, 2, 64);
                ps += __shfl_xor(ps, 4, 64);
                ps += __shfl_xor(ps, 8, 64);
                lrow[r] = lrow[r] * alpha[r] + ps;
                mrow[r] = mnew;
                u16 h0 = f2bf(p0);
                PhS[wave][4 * gp + r][fr]      = h0;
                PlS[wave][4 * gp + r][fr]      = f2bf(p0 - bf2f(h0));
                u16 h1 = f2bf(p1);
                PhS[wave][4 * gp + r][fr + 16] = h1;
                PlS[wave][4 * gp + r][fr + 16] = f2bf(p1 - bf2f(h1));
            }
            #pragma unroll
            for (int f2 = 0; f2 < 8; ++f2)
                #pragma unroll
                for (int r = 0; r < 4; ++r)
                    acc_o[f2][r] *= alpha[r];
            // ---- PV: O[16][128] += P(16x32) . V(32x128)
            short8v ph = *(const short8v*)&PhS[wave][fr][kg];
            short8v pl = *(const short8v*)&PlS[wave][fr][kg];
            #pragma unroll
            for (int f2 = 0; f2 < 8; ++f2) {
                const int bo = VSWZ(fr + 16 * f2, kg);
                short8v vh = *(const short8v*)(VhB + bo);
                short8v vl = *(const short8v*)(VlB + bo);
                acc_o[f2] = __builtin_amdgcn_mfma_f32_16x16x32_bf16(ph, vh, acc_o[f2], 0, 0, 0);
                acc_o[f2] = __builtin_amdgcn_mfma_f32_16x16x32_bf16(ph, vl, acc_o[f2], 0, 0, 0);
                acc_o[f2] = __builtin_amdgcn_mfma_f32_16x16x32_bf16(pl, vh, acc_o[f2], 0, 0, 0);
            }
        }
    }

    // ---- epilogue
    float inv[4];
    #pragma unroll
    for (int r = 0; r < 4; ++r) inv[r] = 1.f / lrow[r];
    #pragma unroll
    for (int r = 0; r < 4; ++r) {
        const size_t t = (size_t)(b * SEQ_LEN + q0 + wave * 16 + 4 * gp + r);
        float* dst = o + t * (NHEAD * 128) + h * 128 + fr;
        #pragma unroll
        for (int f2 = 0; f2 < 8; ++f2)
            dst[16 * f2] = acc_o[f2][r] * inv[r];
    }
}

// ------------------------------- launcher ----------------------------------
extern "C" void kernel_launch(void* const* d_in, const int* in_sizes, int n_in,
                              void* d_out, int out_size, void* d_ws, size_t ws_size,
                              hipStream_t stream)
{
    const float* x         = (const float*)d_in[0];
    const int*   pos       = (const int*)d_in[1];
    const float* w_q_down  = (const float*)d_in[2];
    const float* q_norm_w  = (const float*)d_in[3];
    const float* w_q_up    = (const float*)d_in[4];
    const float* w_kv_down = (const float*)d_in[5];
    const float* kv_norm_w = (const float*)d_in[6];
    const float* w_kv_up   = (const float*)d_in[7];
    const float* w_out     = (const float*)d_in[8];
    float* out = (float*)d_out;

    float* ws = (float*)d_ws;
    float* ao   = ws;                      // attn out aliases q_dn (dead by then)
    float* q_dn = ws;
    float* ckv  = ws + (size_t)T_TOK * 2048;
    float* q_up = ckv + (size_t)T_TOK * (DCKV + DROPE);
    float* kvb  = q_up + (size_t)T_TOK * (NHEAD * QHD);
    float* kr   = kvb + (size_t)T_TOK * (NHEAD * MEGD);
    // total: 4096*(2048+576+3072+4096+64)*4B = 161.5 MB

    dim3 blk(256);
    // q_down: [4096,2048]@[1536,2048]^T
    gemm_split_nt<<<dim3(DCQ / 128, T_TOK / 128), blk, 0, stream>>>(
        x, DMODEL, w_q_down, DMODEL, q_dn, DCQ, DMODEL, DCQ);
    // kv_down: [4096,2048]@[576,2048]^T  (N=576 -> 5 col tiles, guarded)
    gemm_split_nt<<<dim3((DCKV + DROPE + 127) / 128, T_TOK / 128), blk, 0, stream>>>(
        x, DMODEL, w_kv_down, DMODEL, ckv, DCKV + DROPE, DMODEL, DCKV + DROPE);
    rmsnorm_kernel<6><<<T_TOK, 256, 0, stream>>>(q_dn, DCQ, q_norm_w, DCQ);
    rmsnorm_kernel<2><<<T_TOK, 256, 0, stream>>>(ckv, DCKV + DROPE, kv_norm_w, DCKV);
    rope_k_kernel<<<T_TOK / 256, 256, 0, stream>>>(ckv, pos, kr);
    // q_up: [4096,1536]@[3072,1536]^T
    gemm_split_nt<<<dim3((NHEAD * QHD) / 128, T_TOK / 128), blk, 0, stream>>>(
        q_dn, DCQ, w_q_up, DCQ, q_up, NHEAD * QHD, DCQ, NHEAD * QHD);
    // kv_up: [4096,512(stride 576)]@[4096,512]^T
    gemm_split_nt<<<dim3((NHEAD * MEGD) / 128, T_TOK / 128), blk, 0, stream>>>(
        ckv, DCKV + DROPE, w_kv_up, DCKV, kvb, NHEAD * MEGD, DCKV, NHEAD * MEGD);
    rope_q_kernel<<<(T_TOK * NHEAD) / 256, 256, 0, stream>>>(q_up, pos);
    // MFMA attention: grid (S/64, H, B)
    mla_attn_mfma<<<dim3(SEQ_LEN / BQA, NHEAD, NB), dim3(256), 0, stream>>>(
        q_up, kvb, kr, ao);
    // out projection: [4096,2048]@[2048,2048]^T
    gemm_split_nt<<<dim3(DMODEL / 128, T_TOK / 128), blk, 0, stream>>>(
        ao, DMODEL, w_out, DMODEL, out, DMODEL, DMODEL, DMODEL);
}